// Round 8
// baseline (107.811 us; speedup 1.0000x reference)
//
#include <hip/hip_runtime.h>
#include <cstdint>
#include <cstddef>

#define NB 8
#define NS 4096
#define NN 2048
#define NH 768
#define NK 50

// ---------------------------------------------------------------------------
// KD: rowdot[b][c][s] = dot(x[b,s,:], anchor[c,:]).  One wave per 8
// consecutive rows; lane holds h = lane*4 + p*256 (3 float4 per row, fully
// coalesced 1KB wave-loads); 2-row software pipeline; shuffle-reduce; lane 0
// stores 3 f32. Memory-bound streaming of the full 100.7 MB input.
// [UNCHANGED from passing R7]
// ---------------------------------------------------------------------------
__global__ __launch_bounds__(256) void kd_rowdots(const float* __restrict__ x,
                                                  const float* __restrict__ anchor,
                                                  float* __restrict__ rowdot) {
  const int lane = threadIdx.x & 63;
  const int gw   = blockIdx.x * 4 + (threadIdx.x >> 6);   // 0..4095

  float4 a[3][3];
#pragma unroll
  for (int c = 0; c < 3; ++c)
#pragma unroll
    for (int p = 0; p < 3; ++p)
      a[c][p] = *reinterpret_cast<const float4*>(anchor + c * NH + p * 256 + lane * 4);

  const float* base = x + (size_t)gw * 8 * NH + lane * 4;

  float4 va[3], vb[3];
#pragma unroll
  for (int p = 0; p < 3; ++p)
    va[p] = *reinterpret_cast<const float4*>(base + p * 256);

#define KD_LOAD(V, I)                                                         \
  {                                                                           \
    const float* s_ = base + (size_t)(I) * NH;                                \
    _Pragma("unroll")                                                         \
    for (int p = 0; p < 3; ++p)                                               \
      V[p] = *reinterpret_cast<const float4*>(s_ + p * 256);                  \
  }
#define KD_CONS(V, I)                                                         \
  {                                                                           \
    float d0 = 0.f, d1 = 0.f, d2 = 0.f;                                       \
    _Pragma("unroll")                                                         \
    for (int p = 0; p < 3; ++p) {                                             \
      d0 += V[p].x * a[0][p].x + V[p].y * a[0][p].y +                         \
            V[p].z * a[0][p].z + V[p].w * a[0][p].w;                          \
      d1 += V[p].x * a[1][p].x + V[p].y * a[1][p].y +                         \
            V[p].z * a[1][p].z + V[p].w * a[1][p].w;                          \
      d2 += V[p].x * a[2][p].x + V[p].y * a[2][p].y +                         \
            V[p].z * a[2][p].z + V[p].w * a[2][p].w;                          \
    }                                                                         \
    _Pragma("unroll")                                                         \
    for (int o = 32; o > 0; o >>= 1) {                                        \
      d0 += __shfl_xor(d0, o);                                                \
      d1 += __shfl_xor(d1, o);                                                \
      d2 += __shfl_xor(d2, o);                                                \
    }                                                                         \
    if (lane == 0) {                                                          \
      int r = gw * 8 + (I);                                                   \
      int b = r >> 12, s = r & 4095;                                          \
      float* o_ = rowdot + (size_t)b * 3 * NS + s;                            \
      o_[0]      = d0;                                                        \
      o_[NS]     = d1;                                                        \
      o_[2 * NS] = d2;                                                        \
    }                                                                         \
  }

#pragma unroll
  for (int i = 0; i < 8; i += 2) {
    KD_LOAD(vb, i + 1)
    KD_CONS(va, i)
    if (i + 2 < 8) KD_LOAD(va, i + 2)
    KD_CONS(vb, i + 1)
  }
#undef KD_LOAD
#undef KD_CONS
}

// ---------------------------------------------------------------------------
// K3F: fused span-scores + top-50.  One 1024-thread block per batch.
// Each thread computes 2 span scores directly from the L2-resident rowdot
// table (same add order as passing R7 -> bitwise-identical scores), packs
// (orderable score, 2047-index) u64 keys in REGISTERS, then 50 iterations of
// block-argmax: 6-level wave shfl butterfly + 16-entry LDS cross-wave reduce
// (2 barriers/iter, no LDS rescans). Winner zeroed in-register.
// ---------------------------------------------------------------------------
__global__ __launch_bounds__(1024) void k3f_topk(const float* __restrict__ rowdot,
                                                 const int* __restrict__ starts,
                                                 const int* __restrict__ lens,
                                                 int* __restrict__ topidx) {
  const int b   = blockIdx.x;
  const int tid = threadIdx.x;
  const int wid = tid >> 6;
  const int lane = tid & 63;

  __shared__ unsigned long long wred[16];
  __shared__ unsigned long long winner;

  // ---- span scores (bitwise-identical to R7's ks_span) ----
  unsigned long long key0, key1;
#pragma unroll
  for (int half = 0; half < 2; ++half) {
    const int sp = tid + half * 1024;          // span index in batch
    const int st = starts[b * NN + sp];
    const int n  = lens[b * NN + sp] + 1;
    const float* rd = rowdot + (size_t)b * 3 * NS + st;
    float s0 = 0.f, s1 = 0.f, s2 = 0.f;
    for (int r = 0; r < n; ++r) {
      s0 += rd[r];
      s1 += rd[NS + r];
      s2 += rd[2 * NS + r];
    }
    float sc = fmaxf(s0, fmaxf(s1, s2)) / (float)n;
    unsigned u   = __float_as_uint(sc);
    unsigned ord = (u & 0x80000000u) ? ~u : (u | 0x80000000u);
    unsigned long long k = ((unsigned long long)ord << 32) | (unsigned)(NN - 1 - sp);
    if (half == 0) key0 = k; else key1 = k;
  }

  // ---- 50 x block argmax ----
  for (int k = 0; k < NK; ++k) {
    unsigned long long m = (key0 > key1) ? key0 : key1;
#pragma unroll
    for (int o = 32; o > 0; o >>= 1) {
      unsigned long long t = __shfl_xor(m, o);
      if (t > m) m = t;
    }
    if (lane == 0) wred[wid] = m;
    __syncthreads();
    if (tid < 16) {
      unsigned long long mm = wred[tid];
#pragma unroll
      for (int o = 8; o > 0; o >>= 1) {
        unsigned long long t = __shfl_xor(mm, o, 16);
        if (t > mm) mm = t;
      }
      if (tid == 0) winner = mm;
    }
    __syncthreads();
    const unsigned long long wkey = winner;
    const int n = (NN - 1) - (int)(wkey & 0xFFFFFFFFull);
    if (tid == 0) topidx[b * NK + k] = n;
    if (n == tid)        key0 = 0;
    else if (n == tid + 1024) key1 = 0;
  }
}

// ---------------------------------------------------------------------------
// K4a: for the 400 selected spans: emb = (sum of span's x rows)/n_tok
// computed directly (<=8 coalesced row reads, L3-warm), then dot with the 48
// weight rows -> proj[b][k][48] = {rh[4], rt[4], nh[20], nt[20]}. [UNCHANGED]
// ---------------------------------------------------------------------------
__global__ __launch_bounds__(256) void k4a_proj(const float* __restrict__ x,
                                                const int* __restrict__ starts,
                                                const int* __restrict__ lens,
                                                const int* __restrict__ topidx,
                                                const float* __restrict__ rel,
                                                const float* __restrict__ nota,
                                                float* __restrict__ proj) {
  const int gw   = blockIdx.x * 4 + (threadIdx.x >> 6);   // 0..399
  const int lane = threadIdx.x & 63;
  const int b = gw / NK, k = gw % NK;
  const int n  = topidx[b * NK + k];
  const int st = starts[b * NN + n];
  const int nt = lens[b * NN + n] + 1;
  const float fnt = (float)nt;

  float4 e[3];
#pragma unroll
  for (int p = 0; p < 3; ++p) { e[p].x = 0.f; e[p].y = 0.f; e[p].z = 0.f; e[p].w = 0.f; }
  for (int r = 0; r < nt; ++r) {
    const float* row = x + ((size_t)b * NS + st + r) * NH + lane * 4;
#pragma unroll
    for (int p = 0; p < 3; ++p) {
      float4 v = *reinterpret_cast<const float4*>(row + p * 256);
      e[p].x += v.x; e[p].y += v.y; e[p].z += v.z; e[p].w += v.w;
    }
  }
#pragma unroll
  for (int p = 0; p < 3; ++p) {
    e[p].x /= fnt; e[p].y /= fnt; e[p].z /= fnt; e[p].w /= fnt;
  }

  for (int w = 0; w < 48; ++w) {
    const float* wr;
    if (w < 4)       wr = rel  + (size_t)w * (2 * NH);
    else if (w < 8)  wr = rel  + (size_t)(w - 4) * (2 * NH) + NH;
    else if (w < 28) wr = nota + (size_t)(w - 8) * (2 * NH);
    else             wr = nota + (size_t)(w - 28) * (2 * NH) + NH;
    wr += lane * 4;
    float d = 0.f;
#pragma unroll
    for (int p = 0; p < 3; ++p) {
      float4 wv = *reinterpret_cast<const float4*>(wr + p * 256);
      d += e[p].x * wv.x + e[p].y * wv.y + e[p].z * wv.z + e[p].w * wv.w;
    }
#pragma unroll
    for (int o = 32; o > 0; o >>= 1) d += __shfl_xor(d, o);
    if (lane == 0) proj[((size_t)b * NK + k) * 48 + w] = d;
  }
}

// ---------------------------------------------------------------------------
// K4b: out[b,k1,k2,0] = max_m(nh[k1,m]+nt[k2,m]); out[b,k1,k2,1+r] = rh+rt.
// [UNCHANGED]
// ---------------------------------------------------------------------------
__global__ __launch_bounds__(256) void k4b_out(const float* __restrict__ proj,
                                               float* __restrict__ out) {
  int idx = blockIdx.x * 256 + threadIdx.x;
  if (idx >= NB * NK * NK) return;
  int b  = idx / (NK * NK);
  int rr = idx % (NK * NK);
  int k1 = rr / NK, k2 = rr % NK;
  const float* p1 = proj + ((size_t)b * NK + k1) * 48;
  const float* p2 = proj + ((size_t)b * NK + k2) * 48;
  float mx = p1[8] + p2[28];
#pragma unroll
  for (int m = 1; m < 20; ++m) mx = fmaxf(mx, p1[8 + m] + p2[28 + m]);
  float* o = out + (size_t)idx * 5;
  o[0] = mx;
#pragma unroll
  for (int r = 0; r < 4; ++r) o[1 + r] = p1[r] + p2[4 + r];
}

// ---------------------------------------------------------------------------
extern "C" void kernel_launch(void* const* d_in, const int* in_sizes, int n_in,
                              void* d_out, int out_size, void* d_ws, size_t ws_size,
                              hipStream_t stream) {
  const float* x      = (const float*)d_in[0];
  const int*   starts = (const int*)d_in[1];
  const int*   lens   = (const int*)d_in[2];
  const float* anchor = (const float*)d_in[3];
  const float* rel    = (const float*)d_in[4];
  const float* nota   = (const float*)d_in[5];
  float* out = (float*)d_out;

  char* ws = (char*)d_ws;
  float* rowdot = (float*)ws;                                    // 1.5 MB
  int*   topidx = (int*)(ws + (size_t)NB * 3 * NS * sizeof(float));
  float* proj   = (float*)(ws + (size_t)NB * 3 * NS * sizeof(float) + 4096);

  hipLaunchKernelGGL(kd_rowdots, dim3(1024), dim3(256), 0, stream, x, anchor, rowdot);
  hipLaunchKernelGGL(k3f_topk, dim3(NB), dim3(1024), 0, stream,
                     rowdot, starts, lens, topidx);
  hipLaunchKernelGGL(k4a_proj, dim3(NB * NK / 4), dim3(256), 0, stream,
                     x, starts, lens, topidx, rel, nota, proj);
  hipLaunchKernelGGL(k4b_out, dim3((NB * NK * NK + 255) / 256), dim3(256), 0, stream,
                     proj, out);
}

// Round 9
// 68.266 us; speedup vs baseline: 1.5793x; 1.5793x over previous
//
#include <hip/hip_runtime.h>
#include <cstdint>
#include <cstddef>

#define NB 8
#define NS 4096
#define NN 2048
#define NH 768
#define NK 50

// ---------------------------------------------------------------------------
// KD: rowdot[b][c][s] = dot(x[b,s,:], anchor[c,:]). [UNCHANGED from R7/R8]
// ---------------------------------------------------------------------------
__global__ __launch_bounds__(256) void kd_rowdots(const float* __restrict__ x,
                                                  const float* __restrict__ anchor,
                                                  float* __restrict__ rowdot) {
  const int lane = threadIdx.x & 63;
  const int gw   = blockIdx.x * 4 + (threadIdx.x >> 6);   // 0..4095

  float4 a[3][3];
#pragma unroll
  for (int c = 0; c < 3; ++c)
#pragma unroll
    for (int p = 0; p < 3; ++p)
      a[c][p] = *reinterpret_cast<const float4*>(anchor + c * NH + p * 256 + lane * 4);

  const float* base = x + (size_t)gw * 8 * NH + lane * 4;

  float4 va[3], vb[3];
#pragma unroll
  for (int p = 0; p < 3; ++p)
    va[p] = *reinterpret_cast<const float4*>(base + p * 256);

#define KD_LOAD(V, I)                                                         \
  {                                                                           \
    const float* s_ = base + (size_t)(I) * NH;                                \
    _Pragma("unroll")                                                         \
    for (int p = 0; p < 3; ++p)                                               \
      V[p] = *reinterpret_cast<const float4*>(s_ + p * 256);                  \
  }
#define KD_CONS(V, I)                                                         \
  {                                                                           \
    float d0 = 0.f, d1 = 0.f, d2 = 0.f;                                       \
    _Pragma("unroll")                                                         \
    for (int p = 0; p < 3; ++p) {                                             \
      d0 += V[p].x * a[0][p].x + V[p].y * a[0][p].y +                         \
            V[p].z * a[0][p].z + V[p].w * a[0][p].w;                          \
      d1 += V[p].x * a[1][p].x + V[p].y * a[1][p].y +                         \
            V[p].z * a[1][p].z + V[p].w * a[1][p].w;                          \
      d2 += V[p].x * a[2][p].x + V[p].y * a[2][p].y +                         \
            V[p].z * a[2][p].z + V[p].w * a[2][p].w;                          \
    }                                                                         \
    _Pragma("unroll")                                                         \
    for (int o = 32; o > 0; o >>= 1) {                                        \
      d0 += __shfl_xor(d0, o);                                                \
      d1 += __shfl_xor(d1, o);                                                \
      d2 += __shfl_xor(d2, o);                                                \
    }                                                                         \
    if (lane == 0) {                                                          \
      int r = gw * 8 + (I);                                                   \
      int b = r >> 12, s = r & 4095;                                          \
      float* o_ = rowdot + (size_t)b * 3 * NS + s;                            \
      o_[0]      = d0;                                                        \
      o_[NS]     = d1;                                                        \
      o_[2 * NS] = d2;                                                        \
    }                                                                         \
  }

#pragma unroll
  for (int i = 0; i < 8; i += 2) {
    KD_LOAD(vb, i + 1)
    KD_CONS(va, i)
    if (i + 2 < 8) KD_LOAD(va, i + 2)
    KD_CONS(vb, i + 1)
  }
#undef KD_LOAD
#undef KD_CONS
}

// ---------------------------------------------------------------------------
// K3F: fused span-scores + top-50 via radix-2 rank-select (no serial argmax).
// One 1024-thread block per batch; 2 keys/thread in registers.
//  1) scores identical (bitwise) to passing rounds -> u64 key
//     (orderable-score << 32) | (2047 - idx): unique, total order =
//     (score desc, idx asc) = lax.top_k order.
//  2) 16 radix-2 iterations find T = ord of the rank-50 key: per iter
//     6 ballots -> packed per-wave counts -> 2 barriers -> 4-way decision.
//  3) compact keys with ord >= T (~50-80 incl. ties) to LDS; each
//     candidate's global rank = #greater candidates; write ranks < 50.
// ---------------------------------------------------------------------------
__global__ __launch_bounds__(1024) void k3f_topk(const float* __restrict__ rowdot,
                                                 const int* __restrict__ starts,
                                                 const int* __restrict__ lens,
                                                 int* __restrict__ topidx) {
  const int b    = blockIdx.x;
  const int tid  = threadIdx.x;
  const int wid  = tid >> 6;
  const int lane = tid & 63;

  __shared__ unsigned long long wred[16];
  __shared__ unsigned long long cand[NN];
  __shared__ unsigned candcnt;

  // ---- span scores (bitwise-identical to passing rounds) ----
  unsigned long long key0, key1;
#pragma unroll
  for (int half = 0; half < 2; ++half) {
    const int sp = tid + half * 1024;
    const int st = starts[b * NN + sp];
    const int n  = lens[b * NN + sp] + 1;
    const float* rd = rowdot + (size_t)b * 3 * NS + st;
    float s0 = 0.f, s1 = 0.f, s2 = 0.f;
    for (int r = 0; r < n; ++r) {
      s0 += rd[r];
      s1 += rd[NS + r];
      s2 += rd[2 * NS + r];
    }
    float sc = fmaxf(s0, fmaxf(s1, s2)) / (float)n;
    unsigned u   = __float_as_uint(sc);
    unsigned ord = (u & 0x80000000u) ? ~u : (u | 0x80000000u);
    unsigned long long k = ((unsigned long long)ord << 32) | (unsigned)(NN - 1 - sp);
    if (half == 0) key0 = k; else key1 = k;
  }
  const unsigned ord0 = (unsigned)(key0 >> 32);
  const unsigned ord1 = (unsigned)(key1 >> 32);

  // ---- radix-2 MSB-first select: T = ord of the 50th-largest key ----
  unsigned T = 0;
  int rem = NK;
  bool a0 = true, a1 = true;
  for (int bit = 30; bit >= 0; bit -= 2) {
    const int u0 = a0 ? (int)((ord0 >> bit) & 3) : -1;
    const int u1 = a1 ? (int)((ord1 >> bit) & 3) : -1;
    unsigned c3 = __popcll(__ballot(u0 == 3)) + __popcll(__ballot(u1 == 3));
    unsigned c2 = __popcll(__ballot(u0 == 2)) + __popcll(__ballot(u1 == 2));
    unsigned c1 = __popcll(__ballot(u0 == 1)) + __popcll(__ballot(u1 == 1));
    if (lane == 0)
      wred[wid] = ((unsigned long long)c3 << 28) |
                  ((unsigned long long)c2 << 14) | c1;
    __syncthreads();
    unsigned long long s = 0;
#pragma unroll
    for (int i = 0; i < 16; ++i) s += wred[i];
    __syncthreads();                       // wred reusable next iter
    const int C3 = (int)((s >> 28) & 0x3FFF);
    const int C2 = (int)((s >> 14) & 0x3FFF);
    const int C1 = (int)(s & 0x3FFF);
    int d;
    if (C3 >= rem)                 d = 3;
    else if (C3 + C2 >= rem)      { d = 2; rem -= C3; }
    else if (C3 + C2 + C1 >= rem) { d = 1; rem -= C3 + C2; }
    else                          { d = 0; rem -= C3 + C2 + C1; }
    T |= ((unsigned)d) << bit;
    a0 = a0 && (u0 == d);
    a1 = a1 && (u1 == d);
  }

  // ---- compact candidates (ord >= T) ----
  if (tid == 0) candcnt = 0;
  __syncthreads();
  if (ord0 >= T) { unsigned p = atomicAdd(&candcnt, 1u); cand[p] = key0; }
  if (ord1 >= T) { unsigned p = atomicAdd(&candcnt, 1u); cand[p] = key1; }
  __syncthreads();
  const int M = (int)candcnt;              // >= 50 by construction

  // ---- exact rank among candidates; emit ranks < 50 ----
  for (int i = tid; i < M; i += 1024) {
    const unsigned long long ki = cand[i];
    int r = 0;
    for (int j = 0; j < M; ++j) r += (cand[j] > ki);
    if (r < NK)
      topidx[b * NK + r] = (NN - 1) - (int)(ki & 0xFFFFFFFFull);
  }
}

// ---------------------------------------------------------------------------
// K4a: projections for the 400 selected spans. [UNCHANGED]
// ---------------------------------------------------------------------------
__global__ __launch_bounds__(256) void k4a_proj(const float* __restrict__ x,
                                                const int* __restrict__ starts,
                                                const int* __restrict__ lens,
                                                const int* __restrict__ topidx,
                                                const float* __restrict__ rel,
                                                const float* __restrict__ nota,
                                                float* __restrict__ proj) {
  const int gw   = blockIdx.x * 4 + (threadIdx.x >> 6);   // 0..399
  const int lane = threadIdx.x & 63;
  const int b = gw / NK, k = gw % NK;
  const int n  = topidx[b * NK + k];
  const int st = starts[b * NN + n];
  const int nt = lens[b * NN + n] + 1;
  const float fnt = (float)nt;

  float4 e[3];
#pragma unroll
  for (int p = 0; p < 3; ++p) { e[p].x = 0.f; e[p].y = 0.f; e[p].z = 0.f; e[p].w = 0.f; }
  for (int r = 0; r < nt; ++r) {
    const float* row = x + ((size_t)b * NS + st + r) * NH + lane * 4;
#pragma unroll
    for (int p = 0; p < 3; ++p) {
      float4 v = *reinterpret_cast<const float4*>(row + p * 256);
      e[p].x += v.x; e[p].y += v.y; e[p].z += v.z; e[p].w += v.w;
    }
  }
#pragma unroll
  for (int p = 0; p < 3; ++p) {
    e[p].x /= fnt; e[p].y /= fnt; e[p].z /= fnt; e[p].w /= fnt;
  }

  for (int w = 0; w < 48; ++w) {
    const float* wr;
    if (w < 4)       wr = rel  + (size_t)w * (2 * NH);
    else if (w < 8)  wr = rel  + (size_t)(w - 4) * (2 * NH) + NH;
    else if (w < 28) wr = nota + (size_t)(w - 8) * (2 * NH);
    else             wr = nota + (size_t)(w - 28) * (2 * NH) + NH;
    wr += lane * 4;
    float d = 0.f;
#pragma unroll
    for (int p = 0; p < 3; ++p) {
      float4 wv = *reinterpret_cast<const float4*>(wr + p * 256);
      d += e[p].x * wv.x + e[p].y * wv.y + e[p].z * wv.z + e[p].w * wv.w;
    }
#pragma unroll
    for (int o = 32; o > 0; o >>= 1) d += __shfl_xor(d, o);
    if (lane == 0) proj[((size_t)b * NK + k) * 48 + w] = d;
  }
}

// ---------------------------------------------------------------------------
// K4b: epilogue. [UNCHANGED]
// ---------------------------------------------------------------------------
__global__ __launch_bounds__(256) void k4b_out(const float* __restrict__ proj,
                                               float* __restrict__ out) {
  int idx = blockIdx.x * 256 + threadIdx.x;
  if (idx >= NB * NK * NK) return;
  int b  = idx / (NK * NK);
  int rr = idx % (NK * NK);
  int k1 = rr / NK, k2 = rr % NK;
  const float* p1 = proj + ((size_t)b * NK + k1) * 48;
  const float* p2 = proj + ((size_t)b * NK + k2) * 48;
  float mx = p1[8] + p2[28];
#pragma unroll
  for (int m = 1; m < 20; ++m) mx = fmaxf(mx, p1[8 + m] + p2[28 + m]);
  float* o = out + (size_t)idx * 5;
  o[0] = mx;
#pragma unroll
  for (int r = 0; r < 4; ++r) o[1 + r] = p1[r] + p2[4 + r];
}

// ---------------------------------------------------------------------------
extern "C" void kernel_launch(void* const* d_in, const int* in_sizes, int n_in,
                              void* d_out, int out_size, void* d_ws, size_t ws_size,
                              hipStream_t stream) {
  const float* x      = (const float*)d_in[0];
  const int*   starts = (const int*)d_in[1];
  const int*   lens   = (const int*)d_in[2];
  const float* anchor = (const float*)d_in[3];
  const float* rel    = (const float*)d_in[4];
  const float* nota   = (const float*)d_in[5];
  float* out = (float*)d_out;

  char* ws = (char*)d_ws;
  float* rowdot = (float*)ws;                                    // 1.5 MB
  int*   topidx = (int*)(ws + (size_t)NB * 3 * NS * sizeof(float));
  float* proj   = (float*)(ws + (size_t)NB * 3 * NS * sizeof(float) + 4096);

  hipLaunchKernelGGL(kd_rowdots, dim3(1024), dim3(256), 0, stream, x, anchor, rowdot);
  hipLaunchKernelGGL(k3f_topk, dim3(NB), dim3(1024), 0, stream,
                     rowdot, starts, lens, topidx);
  hipLaunchKernelGGL(k4a_proj, dim3(NB * NK / 4), dim3(256), 0, stream,
                     x, starts, lens, topidx, rel, nota, proj);
  hipLaunchKernelGGL(k4b_out, dim3((NB * NK * NK + 255) / 256), dim3(256), 0, stream,
                     proj, out);
}